// Round 12
// baseline (87.668 us; speedup 1.0000x reference)
//
#include <hip/hip_runtime.h>
#include <hip/hip_bf16.h>
#include <cstdint>

#define NBATCH 4
#define NNODE  2048
#define NEDGE  8192
#define ETOT   (NBATCH * NEDGE)   // 32768 edges total
#define NTOT   (NBATCH * NNODE)   // 8192 nodes total

typedef uint32_t u32x4 __attribute__((ext_vector_type(4)));

__device__ __forceinline__ float elu(float x) {
    return x > 0.0f ? x : expm1f(x);
}

// ---------------------------------------------------------------------------
// Kernel 1: FUSED scan + edge1. One wave per EDGE: the wave early-exit-scans
// BOTH Ro row e and Ri row e (two interleaved chains; same expected traffic
// ~9 chunks as two separate waves, but 2x outstanding loads/wave), so it
// holds both endpoints and runs phi_R1 inline, 8-lane-distributed via __shfl
// (~70 wave-inst, hidden under other waves' memory stalls).
// A must be pre-zeroed (hipMemsetAsync) since atomics begin immediately.
// ---------------------------------------------------------------------------
__global__ __launch_bounds__(256, 6)
void in_scan_edge1_kernel(const u32x4* __restrict__ Ro,
                          const u32x4* __restrict__ Ri,
                          const float* __restrict__ X,    // [B,3,N]
                          const float* __restrict__ Ra,   // [B,E,4]
                          const float* __restrict__ W1, const float* __restrict__ b1,
                          const float* __restrict__ W2, const float* __restrict__ b2,
                          const float* __restrict__ W3, const float* __restrict__ b3,
                          const float* __restrict__ W4, const float* __restrict__ b4,
                          int* __restrict__ ro_idx, int* __restrict__ ri_idx,
                          float* __restrict__ Eff,        // [B*E,4]
                          float* __restrict__ A) {        // [B*N,4] pre-zeroed
    __shared__ float sW1[80], sb1[8], sW2[64], sb2[8], sW3[64], sb3[8], sW4[32], sb4[4];
    const int t = threadIdx.x, bs = blockDim.x;
    for (int i = t; i < 80; i += bs) sW1[i] = W1[i];
    for (int i = t; i < 8;  i += bs) sb1[i] = b1[i];
    for (int i = t; i < 64; i += bs) sW2[i] = W2[i];
    for (int i = t; i < 8;  i += bs) sb2[i] = b2[i];
    for (int i = t; i < 64; i += bs) sW3[i] = W3[i];
    for (int i = t; i < 8;  i += bs) sb3[i] = b3[i];
    for (int i = t; i < 32; i += bs) sW4[i] = W4[i];
    for (int i = t; i < 4;  i += bs) sb4[i] = b4[i];
    __syncthreads();

    const int gtid = blockIdx.x * blockDim.x + threadIdx.x;
    const int e    = gtid >> 6;            // edge id (grid sized exactly)
    const int lane = threadIdx.x & 63;

    const u32x4* __restrict__ pa = Ro + (size_t)e * (NNODE / 4);
    const u32x4* __restrict__ pb = Ri + (size_t)e * (NNODE / 4);

    int ro = -1, ri = -1;
    int ca = 0, cb = 0;
    while (true) {
        u32x4 va, vb;
        const bool la = (ro < 0), lb = (ri < 0);   // wave-uniform
        if (la) va = __builtin_nontemporal_load(&pa[ca * 64 + lane]);
        if (lb) vb = __builtin_nontemporal_load(&pb[cb * 64 + lane]);
        if (la) {
            const uint32_t o = va.x | va.y | va.z | va.w;
            const unsigned long long m = __ballot(o != 0u);
            if (m) {
                const int base = ca * 256 + lane * 4;
                int my;
                if      (va.x) my = base;
                else if (va.y) my = base + 1;
                else if (va.z) my = base + 2;
                else           my = base + 3;      // garbage on o==0 lanes, unused
                ro = __shfl(my, (int)(__ffsll(m) - 1));
            } else if (++ca >= NNODE / 256) ro = 0;   // safety (never all-zero)
        }
        if (lb) {
            const uint32_t o = vb.x | vb.y | vb.z | vb.w;
            const unsigned long long m = __ballot(o != 0u);
            if (m) {
                const int base = cb * 256 + lane * 4;
                int my;
                if      (vb.x) my = base;
                else if (vb.y) my = base + 1;
                else if (vb.z) my = base + 2;
                else           my = base + 3;
                ri = __shfl(my, (int)(__ffsll(m) - 1));
            } else if (++cb >= NNODE / 256) ri = 0;
        }
        if (ro >= 0 && ri >= 0) break;
    }
    if (lane == 0) { ro_idx[e] = ro; ri_idx[e] = ri; }

    // ---- phi_R1, 8-lane distributed (lanes >=8 compute unused copies) ----
    const int b  = e >> 13;                 // / NEDGE
    const int jj = lane & 7;
    const float* Xb = X + (long)b * 3 * NNODE;
    float x[10];
    #pragma unroll
    for (int d = 0; d < 3; ++d) x[d]     = Xb[d * NNODE + ro];  // Xi (receiver)
    #pragma unroll
    for (int d = 0; d < 3; ++d) x[3 + d] = Xb[d * NNODE + ri];  // Xo (sender)
    const float4 ra4 = ((const float4*)Ra)[e];
    x[6] = ra4.x; x[7] = ra4.y; x[8] = ra4.z; x[9] = ra4.w;

    float s1 = sb1[jj];
    #pragma unroll
    for (int i = 0; i < 10; ++i) s1 += x[i] * sW1[i * 8 + jj];
    const float h1 = elu(s1);

    float s2 = sb2[jj];
    #pragma unroll
    for (int i = 0; i < 8; ++i) s2 += __shfl(h1, i) * sW2[i * 8 + jj];
    const float h2 = elu(s2);

    float s3 = sb3[jj];
    #pragma unroll
    for (int i = 0; i < 8; ++i) s3 += __shfl(h2, i) * sW3[i * 8 + jj];
    const float h3 = elu(s3);

    const int j4 = lane & 3;
    float s4 = sb4[j4];
    #pragma unroll
    for (int i = 0; i < 8; ++i) s4 += __shfl(h3, i) * sW4[i * 4 + j4];

    if (lane < 4) {
        Eff[(long)e * 4 + lane] = s4;
        atomicAdd(&A[((long)(b * NNODE + ri)) * 4 + lane], s4);
    }
}

// ---------------------------------------------------------------------------
// Kernel 2: per-node phi_O (7->8->8->3, ELU on hidden). (R6 proven form)
// ---------------------------------------------------------------------------
__global__ void in_node_kernel(const float* __restrict__ X,     // [B,3,N]
                               const float* __restrict__ A,     // [B*N,4]
                               const float* __restrict__ W1, const float* __restrict__ b1,
                               const float* __restrict__ W2, const float* __restrict__ b2,
                               const float* __restrict__ W3, const float* __restrict__ b3,
                               float* __restrict__ Xtil) {      // [B*N,3]
    __shared__ float sW1[56], sb1[8], sW2[64], sb2[8], sW3[24], sb3[3];
    const int t = threadIdx.x, bs = blockDim.x;
    for (int i = t; i < 56; i += bs) sW1[i] = W1[i];
    for (int i = t; i < 8;  i += bs) sb1[i] = b1[i];
    for (int i = t; i < 64; i += bs) sW2[i] = W2[i];
    for (int i = t; i < 8;  i += bs) sb2[i] = b2[i];
    for (int i = t; i < 24; i += bs) sW3[i] = W3[i];
    for (int i = t; i < 3;  i += bs) sb3[i] = b3[i];
    __syncthreads();

    const int n = blockIdx.x * blockDim.x + threadIdx.x;
    if (n >= NTOT) return;
    const int b  = n >> 11;           // / NNODE
    const int nn = n & (NNODE - 1);

    float c[7];
    const float* Xb = X + (long)b * 3 * NNODE;
    #pragma unroll
    for (int d = 0; d < 3; ++d) c[d] = Xb[d * NNODE + nn];
    const float4 a4 = ((const float4*)A)[n];
    c[3] = a4.x; c[4] = a4.y; c[5] = a4.z; c[6] = a4.w;

    float h1[8], h2[8];
    #pragma unroll
    for (int j = 0; j < 8; ++j) {
        float s = sb1[j];
        #pragma unroll
        for (int i = 0; i < 7; ++i) s += c[i] * sW1[i * 8 + j];
        h1[j] = elu(s);
    }
    #pragma unroll
    for (int j = 0; j < 8; ++j) {
        float s = sb2[j];
        #pragma unroll
        for (int i = 0; i < 8; ++i) s += h1[i] * sW2[i * 8 + j];
        h2[j] = elu(s);
    }
    #pragma unroll
    for (int j = 0; j < 3; ++j) {
        float s = sb3[j];
        #pragma unroll
        for (int i = 0; i < 8; ++i) s += h2[i] * sW3[i * 3 + j];
        Xtil[(long)n * 3 + j] = s;
    }
}

// ---------------------------------------------------------------------------
// Kernel 3: per-edge phi_R2 (10->8->8->8->1, ELU) + sigmoid. (R6 proven form)
// ---------------------------------------------------------------------------
__global__ void in_edge2_kernel(const float* __restrict__ Xtil,  // [B*N,3]
                                const float* __restrict__ Eff,   // [B*E,4]
                                const int* __restrict__ ro_idx,
                                const int* __restrict__ ri_idx,
                                const float* __restrict__ W1, const float* __restrict__ b1,
                                const float* __restrict__ W2, const float* __restrict__ b2,
                                const float* __restrict__ W3, const float* __restrict__ b3,
                                const float* __restrict__ W4, const float* __restrict__ b4,
                                float* __restrict__ out) {       // [B*E]
    __shared__ float sW1[80], sb1[8], sW2[64], sb2[8], sW3[64], sb3[8], sW4[8], sb4[1];
    const int t = threadIdx.x, bs = blockDim.x;
    for (int i = t; i < 80; i += bs) sW1[i] = W1[i];
    for (int i = t; i < 8;  i += bs) sb1[i] = b1[i];
    for (int i = t; i < 64; i += bs) sW2[i] = W2[i];
    for (int i = t; i < 8;  i += bs) sb2[i] = b2[i];
    for (int i = t; i < 64; i += bs) sW3[i] = W3[i];
    for (int i = t; i < 8;  i += bs) sb3[i] = b3[i];
    for (int i = t; i < 8;  i += bs) sW4[i] = W4[i];
    for (int i = t; i < 1;  i += bs) sb4[i] = b4[i];
    __syncthreads();

    const int e = blockIdx.x * blockDim.x + threadIdx.x;
    if (e >= ETOT) return;
    const int b  = e >> 13;
    const int ro = ro_idx[e] & (NNODE - 1);
    const int ri = ri_idx[e] & (NNODE - 1);

    float x[10];
    const float* Xb = Xtil + (long)b * NNODE * 3;
    #pragma unroll
    for (int d = 0; d < 3; ++d) x[d]     = Xb[(long)ri * 3 + d];   // Xi_t via Ri
    #pragma unroll
    for (int d = 0; d < 3; ++d) x[3 + d] = Xb[(long)ro * 3 + d];   // Xo_t via Ro
    const float4 ef = ((const float4*)Eff)[e];
    x[6] = ef.x; x[7] = ef.y; x[8] = ef.z; x[9] = ef.w;

    float h1[8], h2[8], h3[8];
    #pragma unroll
    for (int j = 0; j < 8; ++j) {
        float s = sb1[j];
        #pragma unroll
        for (int i = 0; i < 10; ++i) s += x[i] * sW1[i * 8 + j];
        h1[j] = elu(s);
    }
    #pragma unroll
    for (int j = 0; j < 8; ++j) {
        float s = sb2[j];
        #pragma unroll
        for (int i = 0; i < 8; ++i) s += h1[i] * sW2[i * 8 + j];
        h2[j] = elu(s);
    }
    #pragma unroll
    for (int j = 0; j < 8; ++j) {
        float s = sb3[j];
        #pragma unroll
        for (int i = 0; i < 8; ++i) s += h2[i] * sW3[i * 8 + j];
        h3[j] = elu(s);
    }
    float s = sb4[0];
    #pragma unroll
    for (int i = 0; i < 8; ++i) s += h3[i] * sW4[i];
    out[e] = 1.0f / (1.0f + expf(-s));
}

extern "C" void kernel_launch(void* const* d_in, const int* in_sizes, int n_in,
                              void* d_out, int out_size, void* d_ws, size_t ws_size,
                              hipStream_t stream) {
    const float* X  = (const float*)d_in[0];
    const float* Ra = (const float*)d_in[1];
    const float* Ro = (const float*)d_in[2];
    const float* Ri = (const float*)d_in[3];
    const float* r1W1 = (const float*)d_in[4];  const float* r1b1 = (const float*)d_in[5];
    const float* r1W2 = (const float*)d_in[6];  const float* r1b2 = (const float*)d_in[7];
    const float* r1W3 = (const float*)d_in[8];  const float* r1b3 = (const float*)d_in[9];
    const float* r1W4 = (const float*)d_in[10]; const float* r1b4 = (const float*)d_in[11];
    const float* r2W1 = (const float*)d_in[12]; const float* r2b1 = (const float*)d_in[13];
    const float* r2W2 = (const float*)d_in[14]; const float* r2b2 = (const float*)d_in[15];
    const float* r2W3 = (const float*)d_in[16]; const float* r2b3 = (const float*)d_in[17];
    const float* r2W4 = (const float*)d_in[18]; const float* r2b4 = (const float*)d_in[19];
    const float* oW1  = (const float*)d_in[20]; const float* ob1  = (const float*)d_in[21];
    const float* oW2  = (const float*)d_in[22]; const float* ob2  = (const float*)d_in[23];
    const float* oW3  = (const float*)d_in[24]; const float* ob3  = (const float*)d_in[25];

    // workspace layout (16B-aligned segments)
    char* ws = (char*)d_ws;
    int*   ro_idx = (int*)(ws + 0);                 // 32768 ints   (128 KiB)
    int*   ri_idx = (int*)(ws + 131072);            // 32768 ints   (128 KiB)
    float* Eff    = (float*)(ws + 262144);          // 131072 f32   (512 KiB)
    float* A      = (float*)(ws + 786432);          // 32768 f32    (128 KiB)
    float* Xtil   = (float*)(ws + 917504);          // 24576 f32    ( 96 KiB)

    // zero the scatter accumulator (atomics start immediately in kernel 1)
    hipMemsetAsync(A, 0, (size_t)NTOT * 4 * sizeof(float), stream);

    // fused scan+edge1: one wave per edge = 32768 waves = 8192 blocks
    in_scan_edge1_kernel<<<ETOT * 64 / 256, 256, 0, stream>>>(
        (const u32x4*)Ro, (const u32x4*)Ri, X, Ra,
        r1W1, r1b1, r1W2, r1b2, r1W3, r1b3, r1W4, r1b4,
        ro_idx, ri_idx, Eff, A);

    in_node_kernel<<<NTOT / 256, 256, 0, stream>>>(X, A,
                                                   oW1, ob1, oW2, ob2, oW3, ob3,
                                                   Xtil);

    in_edge2_kernel<<<ETOT / 256, 256, 0, stream>>>(Xtil, Eff, ro_idx, ri_idx,
                                                    r2W1, r2b1, r2W2, r2b2, r2W3, r2b3, r2W4, r2b4,
                                                    (float*)d_out);
}

// Round 13
// 76.155 us; speedup vs baseline: 1.1512x; 1.1512x over previous
//
#include <hip/hip_runtime.h>
#include <hip/hip_bf16.h>
#include <cstdint>

#define NBATCH 4
#define NNODE  2048
#define NEDGE  8192
#define ETOT   (NBATCH * NEDGE)   // 32768 edges total
#define NTOT   (NBATCH * NNODE)   // 8192 nodes total

typedef uint32_t u32x4 __attribute__((ext_vector_type(4)));

__device__ __forceinline__ float elu(float x) {
    return x > 0.0f ? x : expm1f(x);
}

// ---------------------------------------------------------------------------
// Kernel 1 (R6 form -- best measured across 7 variants): wave-per-row
// early-exit scan. Each wave owns one row (2048 f32 = 8 chunks of 64 lanes
// x 16B); reads chunk-by-chunk, breaks at the first chunk containing the 1.0
// (ballot is wave-uniform). Expected traffic ~4.5/8 of each row (~288 MiB),
// BW-bound at ~4.8 TB/s effective read rate (R7: time tracks traffic).
// nt loads: touch-once stream (cached variant R10 was slower; touched set
// slightly exceeds 256 MiB L3). Also zeroes the scatter accumulator A.
// ---------------------------------------------------------------------------
__global__ void in_idx_kernel(const u32x4* __restrict__ Ro,
                              const u32x4* __restrict__ Ri,
                              int* __restrict__ ro_idx,
                              int* __restrict__ ri_idx,
                              float* __restrict__ A, int a_elems) {
    const int gtid = blockIdx.x * blockDim.x + threadIdx.x;
    if (gtid < a_elems) A[gtid] = 0.0f;

    const int wid  = gtid >> 6;           // global wave id = row id
    const int lane = threadIdx.x & 63;
    const int nrows = 2 * ETOT;           // 65536 (Ro rows then Ri rows)
    if (wid >= nrows) return;

    const bool second = (wid >= ETOT);
    const int  row    = second ? wid - ETOT : wid;
    const u32x4* __restrict__ src = (second ? Ri : Ro) + (size_t)row * (NNODE / 4);
    int* __restrict__ dst = second ? ri_idx : ro_idx;

    #pragma unroll
    for (int c = 0; c < NNODE / 256; ++c) {            // 8 chunks
        const u32x4 v = __builtin_nontemporal_load(&src[c * 64 + lane]);
        const uint32_t o = v.x | v.y | v.z | v.w;
        const unsigned long long found = __ballot(o != 0u);
        if (found) {
            if (o) {
                const int base = c * 256 + lane * 4;
                if      (v.x) dst[row] = base;
                else if (v.y) dst[row] = base + 1;
                else if (v.z) dst[row] = base + 2;
                else          dst[row] = base + 3;
            }
            break;   // ballot result is wave-uniform -> uniform exit
        }
    }
}

// ---------------------------------------------------------------------------
// Kernel 2: per-edge phi_R1 (10->8->8->8->4, ELU) + scatter-add into A.
// ---------------------------------------------------------------------------
__global__ void in_edge1_kernel(const float* __restrict__ X,    // [B,3,N]
                                const float* __restrict__ Ra,   // [B,E,4]
                                const int* __restrict__ ro_idx,
                                const int* __restrict__ ri_idx,
                                const float* __restrict__ W1, const float* __restrict__ b1,
                                const float* __restrict__ W2, const float* __restrict__ b2,
                                const float* __restrict__ W3, const float* __restrict__ b3,
                                const float* __restrict__ W4, const float* __restrict__ b4,
                                float* __restrict__ Eff,       // [B*E,4]
                                float* __restrict__ A) {       // [B*N,4]
    __shared__ float sW1[80], sb1[8], sW2[64], sb2[8], sW3[64], sb3[8], sW4[32], sb4[4];
    const int t = threadIdx.x, bs = blockDim.x;
    for (int i = t; i < 80; i += bs) sW1[i] = W1[i];
    for (int i = t; i < 8;  i += bs) sb1[i] = b1[i];
    for (int i = t; i < 64; i += bs) sW2[i] = W2[i];
    for (int i = t; i < 8;  i += bs) sb2[i] = b2[i];
    for (int i = t; i < 64; i += bs) sW3[i] = W3[i];
    for (int i = t; i < 8;  i += bs) sb3[i] = b3[i];
    for (int i = t; i < 32; i += bs) sW4[i] = W4[i];
    for (int i = t; i < 4;  i += bs) sb4[i] = b4[i];
    __syncthreads();

    const int e = blockIdx.x * blockDim.x + threadIdx.x;
    if (e >= ETOT) return;
    const int b  = e >> 13;                       // / NEDGE
    const int ro = ro_idx[e] & (NNODE - 1);       // mask: garbage -> wrong, not fault
    const int ri = ri_idx[e] & (NNODE - 1);

    float x[10];
    const float* Xb = X + (long)b * 3 * NNODE;
    #pragma unroll
    for (int d = 0; d < 3; ++d) x[d]     = Xb[d * NNODE + ro];  // Xi (receiver)
    #pragma unroll
    for (int d = 0; d < 3; ++d) x[3 + d] = Xb[d * NNODE + ri];  // Xo (sender)
    const float4 ra = ((const float4*)Ra)[e];
    x[6] = ra.x; x[7] = ra.y; x[8] = ra.z; x[9] = ra.w;

    float h1[8], h2[8], h3[8];
    #pragma unroll
    for (int j = 0; j < 8; ++j) {
        float s = sb1[j];
        #pragma unroll
        for (int i = 0; i < 10; ++i) s += x[i] * sW1[i * 8 + j];
        h1[j] = elu(s);
    }
    #pragma unroll
    for (int j = 0; j < 8; ++j) {
        float s = sb2[j];
        #pragma unroll
        for (int i = 0; i < 8; ++i) s += h1[i] * sW2[i * 8 + j];
        h2[j] = elu(s);
    }
    #pragma unroll
    for (int j = 0; j < 8; ++j) {
        float s = sb3[j];
        #pragma unroll
        for (int i = 0; i < 8; ++i) s += h2[i] * sW3[i * 8 + j];
        h3[j] = elu(s);
    }
    float* Arow = A + ((long)(b * NNODE + ri)) * 4;
    float4 eff;
    float* effp = (float*)&eff;
    #pragma unroll
    for (int j = 0; j < 4; ++j) {
        float s = sb4[j];
        #pragma unroll
        for (int i = 0; i < 8; ++i) s += h3[i] * sW4[i * 4 + j];
        effp[j] = s;
        atomicAdd(&Arow[j], s);
    }
    ((float4*)Eff)[e] = eff;
}

// ---------------------------------------------------------------------------
// Kernel 3: per-node phi_O (7->8->8->3, ELU on hidden).
// ---------------------------------------------------------------------------
__global__ void in_node_kernel(const float* __restrict__ X,     // [B,3,N]
                               const float* __restrict__ A,     // [B*N,4]
                               const float* __restrict__ W1, const float* __restrict__ b1,
                               const float* __restrict__ W2, const float* __restrict__ b2,
                               const float* __restrict__ W3, const float* __restrict__ b3,
                               float* __restrict__ Xtil) {      // [B*N,3]
    __shared__ float sW1[56], sb1[8], sW2[64], sb2[8], sW3[24], sb3[3];
    const int t = threadIdx.x, bs = blockDim.x;
    for (int i = t; i < 56; i += bs) sW1[i] = W1[i];
    for (int i = t; i < 8;  i += bs) sb1[i] = b1[i];
    for (int i = t; i < 64; i += bs) sW2[i] = W2[i];
    for (int i = t; i < 8;  i += bs) sb2[i] = b2[i];
    for (int i = t; i < 24; i += bs) sW3[i] = W3[i];
    for (int i = t; i < 3;  i += bs) sb3[i] = b3[i];
    __syncthreads();

    const int n = blockIdx.x * blockDim.x + threadIdx.x;
    if (n >= NTOT) return;
    const int b  = n >> 11;           // / NNODE
    const int nn = n & (NNODE - 1);

    float c[7];
    const float* Xb = X + (long)b * 3 * NNODE;
    #pragma unroll
    for (int d = 0; d < 3; ++d) c[d] = Xb[d * NNODE + nn];
    const float4 a4 = ((const float4*)A)[n];
    c[3] = a4.x; c[4] = a4.y; c[5] = a4.z; c[6] = a4.w;

    float h1[8], h2[8];
    #pragma unroll
    for (int j = 0; j < 8; ++j) {
        float s = sb1[j];
        #pragma unroll
        for (int i = 0; i < 7; ++i) s += c[i] * sW1[i * 8 + j];
        h1[j] = elu(s);
    }
    #pragma unroll
    for (int j = 0; j < 8; ++j) {
        float s = sb2[j];
        #pragma unroll
        for (int i = 0; i < 8; ++i) s += h1[i] * sW2[i * 8 + j];
        h2[j] = elu(s);
    }
    #pragma unroll
    for (int j = 0; j < 3; ++j) {
        float s = sb3[j];
        #pragma unroll
        for (int i = 0; i < 8; ++i) s += h2[i] * sW3[i * 3 + j];
        Xtil[(long)n * 3 + j] = s;
    }
}

// ---------------------------------------------------------------------------
// Kernel 4: per-edge phi_R2 (10->8->8->8->1, ELU) + sigmoid -> f32 out.
// ---------------------------------------------------------------------------
__global__ void in_edge2_kernel(const float* __restrict__ Xtil,  // [B*N,3]
                                const float* __restrict__ Eff,   // [B*E,4]
                                const int* __restrict__ ro_idx,
                                const int* __restrict__ ri_idx,
                                const float* __restrict__ W1, const float* __restrict__ b1,
                                const float* __restrict__ W2, const float* __restrict__ b2,
                                const float* __restrict__ W3, const float* __restrict__ b3,
                                const float* __restrict__ W4, const float* __restrict__ b4,
                                float* __restrict__ out) {       // [B*E]
    __shared__ float sW1[80], sb1[8], sW2[64], sb2[8], sW3[64], sb3[8], sW4[8], sb4[1];
    const int t = threadIdx.x, bs = blockDim.x;
    for (int i = t; i < 80; i += bs) sW1[i] = W1[i];
    for (int i = t; i < 8;  i += bs) sb1[i] = b1[i];
    for (int i = t; i < 64; i += bs) sW2[i] = W2[i];
    for (int i = t; i < 8;  i += bs) sb2[i] = b2[i];
    for (int i = t; i < 64; i += bs) sW3[i] = W3[i];
    for (int i = t; i < 8;  i += bs) sb3[i] = b3[i];
    for (int i = t; i < 8;  i += bs) sW4[i] = W4[i];
    for (int i = t; i < 1;  i += bs) sb4[i] = b4[i];
    __syncthreads();

    const int e = blockIdx.x * blockDim.x + threadIdx.x;
    if (e >= ETOT) return;
    const int b  = e >> 13;
    const int ro = ro_idx[e] & (NNODE - 1);
    const int ri = ri_idx[e] & (NNODE - 1);

    float x[10];
    const float* Xb = Xtil + (long)b * NNODE * 3;
    #pragma unroll
    for (int d = 0; d < 3; ++d) x[d]     = Xb[(long)ri * 3 + d];   // Xi_t via Ri
    #pragma unroll
    for (int d = 0; d < 3; ++d) x[3 + d] = Xb[(long)ro * 3 + d];   // Xo_t via Ro
    const float4 ef = ((const float4*)Eff)[e];
    x[6] = ef.x; x[7] = ef.y; x[8] = ef.z; x[9] = ef.w;

    float h1[8], h2[8], h3[8];
    #pragma unroll
    for (int j = 0; j < 8; ++j) {
        float s = sb1[j];
        #pragma unroll
        for (int i = 0; i < 10; ++i) s += x[i] * sW1[i * 8 + j];
        h1[j] = elu(s);
    }
    #pragma unroll
    for (int j = 0; j < 8; ++j) {
        float s = sb2[j];
        #pragma unroll
        for (int i = 0; i < 8; ++i) s += h1[i] * sW2[i * 8 + j];
        h2[j] = elu(s);
    }
    #pragma unroll
    for (int j = 0; j < 8; ++j) {
        float s = sb3[j];
        #pragma unroll
        for (int i = 0; i < 8; ++i) s += h2[i] * sW3[i * 8 + j];
        h3[j] = elu(s);
    }
    float s = sb4[0];
    #pragma unroll
    for (int i = 0; i < 8; ++i) s += h3[i] * sW4[i];
    out[e] = 1.0f / (1.0f + expf(-s));
}

extern "C" void kernel_launch(void* const* d_in, const int* in_sizes, int n_in,
                              void* d_out, int out_size, void* d_ws, size_t ws_size,
                              hipStream_t stream) {
    const float* X  = (const float*)d_in[0];
    const float* Ra = (const float*)d_in[1];
    const float* Ro = (const float*)d_in[2];
    const float* Ri = (const float*)d_in[3];
    const float* r1W1 = (const float*)d_in[4];  const float* r1b1 = (const float*)d_in[5];
    const float* r1W2 = (const float*)d_in[6];  const float* r1b2 = (const float*)d_in[7];
    const float* r1W3 = (const float*)d_in[8];  const float* r1b3 = (const float*)d_in[9];
    const float* r1W4 = (const float*)d_in[10]; const float* r1b4 = (const float*)d_in[11];
    const float* r2W1 = (const float*)d_in[12]; const float* r2b1 = (const float*)d_in[13];
    const float* r2W2 = (const float*)d_in[14]; const float* r2b2 = (const float*)d_in[15];
    const float* r2W3 = (const float*)d_in[16]; const float* r2b3 = (const float*)d_in[17];
    const float* r2W4 = (const float*)d_in[18]; const float* r2b4 = (const float*)d_in[19];
    const float* oW1  = (const float*)d_in[20]; const float* ob1  = (const float*)d_in[21];
    const float* oW2  = (const float*)d_in[22]; const float* ob2  = (const float*)d_in[23];
    const float* oW3  = (const float*)d_in[24]; const float* ob3  = (const float*)d_in[25];

    // workspace layout (16B-aligned segments)
    char* ws = (char*)d_ws;
    int*   ro_idx = (int*)(ws + 0);                 // 32768 ints   (128 KiB)
    int*   ri_idx = (int*)(ws + 131072);            // 32768 ints   (128 KiB)
    float* Eff    = (float*)(ws + 262144);          // 131072 f32   (512 KiB)
    float* A      = (float*)(ws + 786432);          // 32768 f32    (128 KiB)
    float* Xtil   = (float*)(ws + 917504);          // 24576 f32    ( 96 KiB)

    // one wave per row: 2*ETOT rows = 65536 waves
    in_idx_kernel<<<(2 * ETOT * 64) / 256, 256, 0, stream>>>(
        (const u32x4*)Ro, (const u32x4*)Ri, ro_idx, ri_idx, A, NTOT * 4 /* 32768 */);

    in_edge1_kernel<<<ETOT / 256, 256, 0, stream>>>(X, Ra, ro_idx, ri_idx,
                                                    r1W1, r1b1, r1W2, r1b2, r1W3, r1b3, r1W4, r1b4,
                                                    Eff, A);

    in_node_kernel<<<NTOT / 256, 256, 0, stream>>>(X, A,
                                                   oW1, ob1, oW2, ob2, oW3, ob3,
                                                   Xtil);

    in_edge2_kernel<<<ETOT / 256, 256, 0, stream>>>(Xtil, Eff, ro_idx, ri_idx,
                                                    r2W1, r2b1, r2W2, r2b2, r2W3, r2b3, r2W4, r2b4,
                                                    (float*)d_out);
}